// Round 1
// baseline (680.686 us; speedup 1.0000x reference)
//
#include <hip/hip_runtime.h>

#define NNODES 50000
#define NEDGES 600000
#define CH 128
#define NGRAPHS 512
#define BN_EPS 1e-5f

// ---------------------------------------------------------------- CSR build
__global__ __launch_bounds__(256) void hist_kernel(const int* __restrict__ dst,
                                                   int* __restrict__ counts, int E) {
    int i = blockIdx.x * 256 + threadIdx.x;
    if (i < E) atomicAdd(&counts[dst[i]], 1);
}

__global__ __launch_bounds__(256) void scan1_kernel(const int* __restrict__ counts,
                                                    int* __restrict__ partials, int n) {
    __shared__ int s[256];
    int i = blockIdx.x * 256 + threadIdx.x;
    int v = (i < n) ? counts[i] : 0;
    s[threadIdx.x] = v;
    __syncthreads();
    for (int off = 128; off > 0; off >>= 1) {
        if (threadIdx.x < off) s[threadIdx.x] += s[threadIdx.x + off];
        __syncthreads();
    }
    if (threadIdx.x == 0) partials[blockIdx.x] = s[0];
}

__global__ void scan2_kernel(int* __restrict__ partials, int nb,
                             int* __restrict__ row_ptr, int total) {
    if (threadIdx.x == 0 && blockIdx.x == 0) {
        int acc = 0;
        for (int i = 0; i < nb; i++) { int v = partials[i]; partials[i] = acc; acc += v; }
        row_ptr[NNODES] = total;
    }
}

__global__ __launch_bounds__(256) void scan3_kernel(const int* __restrict__ counts,
                                                    const int* __restrict__ partials,
                                                    int* __restrict__ row_ptr,
                                                    int* __restrict__ cursor, int n) {
    __shared__ int s[256];
    int i = blockIdx.x * 256 + threadIdx.x;
    int v = (i < n) ? counts[i] : 0;
    s[threadIdx.x] = v;
    __syncthreads();
    // inclusive Hillis-Steele scan (double-barrier form)
    for (int off = 1; off < 256; off <<= 1) {
        int nv = (threadIdx.x >= (unsigned)off) ? s[threadIdx.x - off] : 0;
        __syncthreads();
        s[threadIdx.x] += nv;
        __syncthreads();
    }
    if (i < n) {
        int ex = partials[blockIdx.x] + s[threadIdx.x] - v;  // exclusive
        row_ptr[i] = ex;
        cursor[i] = ex;
    }
}

__global__ __launch_bounds__(256) void scatter_kernel(const int* __restrict__ src,
                                                      const int* __restrict__ dst,
                                                      int* __restrict__ cursor,
                                                      int* __restrict__ esrc, int E) {
    int i = blockIdx.x * 256 + threadIdx.x;
    if (i < E) {
        int p = atomicAdd(&cursor[dst[i]], 1);
        esrc[p] = src[i];
    }
}

// ------------------------------------------------------------- aggregation
// one wave (64 lanes) per node; each lane owns 2 channels (float2 = 8B)
__global__ __launch_bounds__(256) void agg_kernel(const float* __restrict__ x,
                                                  const int* __restrict__ rp,
                                                  const int* __restrict__ esrc,
                                                  float* __restrict__ out, int n) {
    int gid  = blockIdx.x * 256 + threadIdx.x;
    int node = gid >> 6;
    int lane = threadIdx.x & 63;
    if (node >= n) return;
    const float2* x2 = (const float2*)x;
    float2 acc = x2[(size_t)node * 64 + lane];   // + self term (eps=0)
    int beg = rp[node], end = rp[node + 1];
    for (int e = beg; e < end; e++) {
        int s = esrc[e];                          // wave-uniform -> scalar load
        float2 v = x2[(size_t)s * 64 + lane];
        acc.x += v.x; acc.y += v.y;
    }
    ((float2*)out)[(size_t)node * 64 + lane] = acc;
}

// ------------------------------------------------------------------- GEMM
// C[M,128] = A[M,128] @ W[128,128] + epilogue.
// MODE 0: +bias     MODE 1: +bias, relu     MODE 2: +bias, BN(eval), relu
// Block: 256 thr, tile 64 rows x 128 cols. A tile in LDS (pad 132), W staged
// in 32-row chunks. Thread tile: 4 rows x 8 cols. In-place (C==A) is safe:
// each block stages its own 64 A-rows in LDS before any store.
template <int MODE>
__global__ __launch_bounds__(256) void gemm_kernel(
    const float* __restrict__ A, float* __restrict__ C,
    const float* __restrict__ W, const float* __restrict__ bias,
    const float* __restrict__ gm, const float* __restrict__ bt,
    const float* __restrict__ rm, const float* __restrict__ rv, int M) {
    __shared__ float As[64 * 132];
    __shared__ float Bs[32 * 128];
    const int t = threadIdx.x;
    const int row0 = blockIdx.x * 64;

    // stage A tile: 2048 float4s
#pragma unroll
    for (int i = 0; i < 8; i++) {
        int idx = t + i * 256;
        int r = idx >> 5, c4 = idx & 31;
        float4 v = make_float4(0.f, 0.f, 0.f, 0.f);
        if (row0 + r < M) v = *(const float4*)(A + (size_t)(row0 + r) * 128 + c4 * 4);
        *(float4*)&As[r * 132 + c4 * 4] = v;
    }

    const int tc = t & 15;   // 8 cols: tc*8 .. tc*8+7
    const int tr = t >> 4;   // 4 rows: tr*4 .. tr*4+3
    float acc[4][8];
#pragma unroll
    for (int i = 0; i < 4; i++)
#pragma unroll
        for (int j = 0; j < 8; j++) acc[i][j] = 0.f;

    for (int kb = 0; kb < 4; kb++) {
#pragma unroll
        for (int i = 0; i < 4; i++) {
            int idx = t + i * 256;  // 1024 float4 = 32 rows x 128 cols
            *(float4*)&Bs[idx * 4] = *(const float4*)(W + kb * 32 * 128 + idx * 4);
        }
        __syncthreads();   // covers As on first iteration too
#pragma unroll 8
        for (int k = 0; k < 32; k++) {
            float4 b0 = *(const float4*)&Bs[k * 128 + tc * 8];
            float4 b1 = *(const float4*)&Bs[k * 128 + tc * 8 + 4];
#pragma unroll
            for (int i = 0; i < 4; i++) {
                float a = As[(tr * 4 + i) * 132 + kb * 32 + k];
                acc[i][0] += a * b0.x; acc[i][1] += a * b0.y;
                acc[i][2] += a * b0.z; acc[i][3] += a * b0.w;
                acc[i][4] += a * b1.x; acc[i][5] += a * b1.y;
                acc[i][6] += a * b1.z; acc[i][7] += a * b1.w;
            }
        }
        __syncthreads();
    }

    // epilogue constants per column
    float cs[8], ca[8];
#pragma unroll
    for (int j = 0; j < 8; j++) {
        int n = tc * 8 + j;
        if (MODE == 2) {
            float s = gm[n] * rsqrtf(rv[n] + BN_EPS);
            cs[j] = s;
            ca[j] = (bias[n] - rm[n]) * s + bt[n];
        } else {
            cs[j] = 1.f;
            ca[j] = bias[n];
        }
    }
#pragma unroll
    for (int i = 0; i < 4; i++) {
        int r = row0 + tr * 4 + i;
        if (r < M) {
            float o[8];
#pragma unroll
            for (int j = 0; j < 8; j++) {
                float v = acc[i][j] * cs[j] + ca[j];
                if (MODE >= 1) v = fmaxf(v, 0.f);
                o[j] = v;
            }
            *(float4*)(C + (size_t)r * 128 + tc * 8)     = make_float4(o[0], o[1], o[2], o[3]);
            *(float4*)(C + (size_t)r * 128 + tc * 8 + 4) = make_float4(o[4], o[5], o[6], o[7]);
        }
    }
}

// ----------------------------------------------------------------- pooling
__global__ __launch_bounds__(128) void pool_kernel(const float* __restrict__ x1,
                                                   const float* __restrict__ x2,
                                                   const float* __restrict__ x3,
                                                   const int* __restrict__ batch,
                                                   float* __restrict__ pooled, int n) {
    int g = blockIdx.x;
    int t = threadIdx.x;
    // lower_bound(batch, g) and lower_bound(batch, g+1) — batch is sorted
    int lo = 0, hi = n;
    while (lo < hi) { int mid = (lo + hi) >> 1; if (batch[mid] < g) lo = mid + 1; else hi = mid; }
    int start = lo;
    int lo2 = start, hi2 = n;
    while (lo2 < hi2) { int mid = (lo2 + hi2) >> 1; if (batch[mid] < g + 1) lo2 = mid + 1; else hi2 = mid; }
    int end = lo2;

    float s1 = 0.f, s2 = 0.f, s3 = 0.f;
    for (int i = start; i < end; i++) {
        s1 += x1[(size_t)i * 128 + t];
        s2 += x2[(size_t)i * 128 + t];
        s3 += x3[(size_t)i * 128 + t];
    }
    int c = end - start;
    float inv = 1.0f / (c > 0 ? (float)c : 1.0f);
    pooled[g * 384 + t]       = s1 * inv;
    pooled[g * 384 + 128 + t] = s2 * inv;
    pooled[g * 384 + 256 + t] = s3 * inv;
}

__global__ __launch_bounds__(128) void final_kernel(const float* __restrict__ pooled,
                                                    const float* __restrict__ W,
                                                    const float* __restrict__ b,
                                                    float* __restrict__ out) {
    __shared__ float ps[384];
    int g = blockIdx.x, t = threadIdx.x;
    for (int i = t; i < 384; i += 128) ps[i] = pooled[g * 384 + i];
    __syncthreads();
    float acc = b[t];
#pragma unroll 4
    for (int k = 0; k < 384; k++) acc += ps[k] * W[k * 128 + t];
    out[g * 128 + t] = acc;
}

// ------------------------------------------------------------------ launch
extern "C" void kernel_launch(void* const* d_in, const int* in_sizes, int n_in,
                              void* d_out, int out_size, void* d_ws, size_t ws_size,
                              hipStream_t stream) {
    const float* x     = (const float*)d_in[0];
    const int*   edge  = (const int*)d_in[1];
    const int*   batch = (const int*)d_in[2];
    const float* p[32];
    for (int i = 0; i < n_in && i < 32; i++) p[i] = (const float*)d_in[i];
    const float* lin_W = p[27];
    const float* lin_b = p[28];

    char* w = (char*)d_ws;
    auto alloc = [&](size_t bytes) { void* r = (void*)w; w += (bytes + 255) & ~(size_t)255; return r; };
    float* tmp    = (float*)alloc((size_t)NNODES * 128 * 4);
    float* x1     = (float*)alloc((size_t)NNODES * 128 * 4);
    float* x2b    = (float*)alloc((size_t)NNODES * 128 * 4);
    float* x3b    = (float*)alloc((size_t)NNODES * 128 * 4);
    float* pooled = (float*)alloc((size_t)NGRAPHS * 384 * 4);
    int* counts   = (int*)alloc((size_t)NNODES * 4);
    int* cursor   = (int*)alloc((size_t)NNODES * 4);
    int* row_ptr  = (int*)alloc((size_t)(NNODES + 1) * 4);
    int* esrc     = (int*)alloc((size_t)NEDGES * 4);
    int* partials = (int*)alloc(256 * 4);

    const int* src = edge;
    const int* dst = edge + NEDGES;

    // --- CSR build (once per call, reused by all 3 layers)
    hipMemsetAsync(counts, 0, (size_t)NNODES * 4, stream);
    hist_kernel<<<(NEDGES + 255) / 256, 256, 0, stream>>>(dst, counts, NEDGES);
    int nb = (NNODES + 255) / 256;  // 196
    scan1_kernel<<<nb, 256, 0, stream>>>(counts, partials, NNODES);
    scan2_kernel<<<1, 64, 0, stream>>>(partials, nb, row_ptr, NEDGES);
    scan3_kernel<<<nb, 256, 0, stream>>>(counts, partials, row_ptr, cursor, NNODES);
    scatter_kernel<<<(NEDGES + 255) / 256, 256, 0, stream>>>(src, dst, cursor, esrc, NEDGES);

    // --- 3 GIN layers
    const float* xin = x;
    float* outs[3] = {x1, x2b, x3b};
    int gemm_grid = (NNODES + 63) / 64;
    for (int li = 0; li < 3; li++) {
        const float* W1 = p[3 + 8 * li];
        const float* b1 = p[4 + 8 * li];
        const float* gm = p[5 + 8 * li];
        const float* bt = p[6 + 8 * li];
        const float* rm = p[7 + 8 * li];
        const float* rv = p[8 + 8 * li];
        const float* W2 = p[9 + 8 * li];
        const float* b2 = p[10 + 8 * li];

        agg_kernel<<<(NNODES * 64 + 255) / 256, 256, 0, stream>>>(xin, row_ptr, esrc, tmp, NNODES);
        gemm_kernel<2><<<gemm_grid, 256, 0, stream>>>(tmp, tmp, W1, b1, gm, bt, rm, rv, NNODES);
        if (li < 2)
            gemm_kernel<1><<<gemm_grid, 256, 0, stream>>>(tmp, outs[li], W2, b2,
                                                          nullptr, nullptr, nullptr, nullptr, NNODES);
        else
            gemm_kernel<0><<<gemm_grid, 256, 0, stream>>>(tmp, outs[li], W2, b2,
                                                          nullptr, nullptr, nullptr, nullptr, NNODES);
        xin = outs[li];
    }

    // --- JK-concat mean pool + final linear
    pool_kernel<<<NGRAPHS, 128, 0, stream>>>(x1, x2b, x3b, batch, pooled, NNODES);
    final_kernel<<<NGRAPHS, 128, 0, stream>>>(pooled, lin_W, lin_b, (float*)d_out);
}

// Round 2
// 602.714 us; speedup vs baseline: 1.1294x; 1.1294x over previous
//
#include <hip/hip_runtime.h>

#define NNODES 50000
#define NEDGES 600000
#define CH 128
#define NGRAPHS 512
#define BN_EPS 1e-5f

// ---------------------------------------------------------------- CSR build
__global__ __launch_bounds__(256) void hist_kernel(const int* __restrict__ dst,
                                                   int* __restrict__ counts, int E) {
    int i = blockIdx.x * 256 + threadIdx.x;
    if (i < E) atomicAdd(&counts[dst[i]], 1);
}

__global__ __launch_bounds__(256) void scan1_kernel(const int* __restrict__ counts,
                                                    int* __restrict__ partials, int n) {
    __shared__ int s[256];
    int i = blockIdx.x * 256 + threadIdx.x;
    int v = (i < n) ? counts[i] : 0;
    s[threadIdx.x] = v;
    __syncthreads();
    for (int off = 128; off > 0; off >>= 1) {
        if (threadIdx.x < off) s[threadIdx.x] += s[threadIdx.x + off];
        __syncthreads();
    }
    if (threadIdx.x == 0) partials[blockIdx.x] = s[0];
}

// block-scan over the (<=256) per-block partials; was a 1-thread serial loop.
__global__ __launch_bounds__(256) void scan2_kernel(int* __restrict__ partials, int nb,
                                                    int* __restrict__ row_ptr, int total) {
    __shared__ int s[256];
    int t = threadIdx.x;
    int v = (t < nb) ? partials[t] : 0;
    s[t] = v;
    __syncthreads();
    for (int off = 1; off < 256; off <<= 1) {
        int nv = (t >= off) ? s[t - off] : 0;
        __syncthreads();
        s[t] += nv;
        __syncthreads();
    }
    if (t < nb) partials[t] = s[t] - v;   // exclusive
    if (t == 0) row_ptr[NNODES] = total;
}

__global__ __launch_bounds__(256) void scan3_kernel(const int* __restrict__ counts,
                                                    const int* __restrict__ partials,
                                                    int* __restrict__ row_ptr,
                                                    int* __restrict__ cursor, int n) {
    __shared__ int s[256];
    int i = blockIdx.x * 256 + threadIdx.x;
    int v = (i < n) ? counts[i] : 0;
    s[threadIdx.x] = v;
    __syncthreads();
    for (int off = 1; off < 256; off <<= 1) {
        int nv = (threadIdx.x >= (unsigned)off) ? s[threadIdx.x - off] : 0;
        __syncthreads();
        s[threadIdx.x] += nv;
        __syncthreads();
    }
    if (i < n) {
        int ex = partials[blockIdx.x] + s[threadIdx.x] - v;  // exclusive
        row_ptr[i] = ex;
        cursor[i] = ex;
    }
}

__global__ __launch_bounds__(256) void scatter_kernel(const int* __restrict__ src,
                                                      const int* __restrict__ dst,
                                                      int* __restrict__ cursor,
                                                      int* __restrict__ esrc, int E) {
    int i = blockIdx.x * 256 + threadIdx.x;
    if (i < E) {
        int p = atomicAdd(&cursor[dst[i]], 1);
        esrc[p] = src[i];
    }
}

// ------------------------------------------------------------- aggregation
// one wave per node; lane owns 2 channels. Unroll-by-4 to break the
// dependent esrc->x load chain (was latency-bound: VALUBusy 10%, hbm 30%).
__global__ __launch_bounds__(256) void agg_kernel(const float* __restrict__ x,
                                                  const int* __restrict__ rp,
                                                  const int* __restrict__ esrc,
                                                  float* __restrict__ out, int n) {
    int gid  = blockIdx.x * 256 + threadIdx.x;
    int node = gid >> 6;
    int lane = threadIdx.x & 63;
    if (node >= n) return;
    const float2* x2 = (const float2*)x;
    float2 acc = x2[(size_t)node * 64 + lane];   // self term (eps=0)
    int beg = rp[node], end = rp[node + 1];
    int e = beg;
    for (; e + 4 <= end; e += 4) {
        int s0 = esrc[e], s1 = esrc[e + 1], s2 = esrc[e + 2], s3 = esrc[e + 3];
        float2 v0 = x2[(size_t)s0 * 64 + lane];
        float2 v1 = x2[(size_t)s1 * 64 + lane];
        float2 v2 = x2[(size_t)s2 * 64 + lane];
        float2 v3 = x2[(size_t)s3 * 64 + lane];
        acc.x += (v0.x + v1.x) + (v2.x + v3.x);
        acc.y += (v0.y + v1.y) + (v2.y + v3.y);
    }
    for (; e < end; e++) {
        int s = esrc[e];
        float2 v = x2[(size_t)s * 64 + lane];
        acc.x += v.x; acc.y += v.y;
    }
    ((float2*)out)[(size_t)node * 64 + lane] = acc;
}

// ------------------------------------------------------------------- GEMM
// C[M,128] = A[M,128] @ W[128,128] + epilogue.
// MODE 0: +bias   MODE 1: +bias,relu   MODE 2: +bias,BN(eval),relu
// 256 thr, M-tile 128, full N=128. Thread tile 8x8 (64 FMA/k = 128 wave-cyc
// vs ~62 cyc LDS -> VALU-bound). A staged k-major (transposed) so inner loop
// is pure ds_read_b128. LDS 33.8KB -> 4 blocks/CU.
// In-place safe: all A reads of a block happen before its epilogue stores,
// and blocks touch disjoint row ranges.
template <int MODE>
__global__ __launch_bounds__(256) void gemm_kernel(
    const float* __restrict__ A, float* __restrict__ C,
    const float* __restrict__ W, const float* __restrict__ bias,
    const float* __restrict__ gm, const float* __restrict__ bt,
    const float* __restrict__ rm, const float* __restrict__ rv, int M) {
    __shared__ float As[32 * 132];   // k-major: As[k*132 + m]
    __shared__ float Ws[32 * 132];   // k-major: Ws[k*132 + n]
    const int t = threadIdx.x;
    const int row0 = blockIdx.x * 128;
    const int tr = t >> 4;           // 0..15 -> rows tr*8..+7
    const int tc = t & 15;           // 0..15 -> cols tc*8..+7

    const int ar = t >> 1;           // 0..127 A-row
    const int ah = t & 1;            // A col-half (16 floats)
    const int wr = t >> 3;           // 0..31  W k-row
    const int wsg = t & 7;           // W col-seg (16 floats)

    float acc[8][8];
#pragma unroll
    for (int i = 0; i < 8; i++)
#pragma unroll
        for (int j = 0; j < 8; j++) acc[i][j] = 0.f;

    for (int kb = 0; kb < 4; kb++) {
        // --- stage A chunk (rows row0..+127, k = kb*32..+31), transposed
        {
            float4 v[4];
            int r = row0 + ar;
            if (r < M) {
                const float4* ap = (const float4*)(A + (size_t)r * 128 + kb * 32 + ah * 16);
                v[0] = ap[0]; v[1] = ap[1]; v[2] = ap[2]; v[3] = ap[3];
            } else {
                v[0] = v[1] = v[2] = v[3] = make_float4(0.f, 0.f, 0.f, 0.f);
            }
            const float* vf = (const float*)v;
#pragma unroll
            for (int j = 0; j < 16; j++)
                As[(ah * 16 + j) * 132 + ar] = vf[j];
        }
        // --- stage W chunk (k = kb*32..+31, all 128 cols)
        {
            const float4* wp = (const float4*)(W + (size_t)(kb * 32 + wr) * 128 + wsg * 16);
            float4* dp = (float4*)&Ws[wr * 132 + wsg * 16];
            dp[0] = wp[0]; dp[1] = wp[1]; dp[2] = wp[2]; dp[3] = wp[3];
        }
        __syncthreads();

#pragma unroll 4
        for (int k = 0; k < 32; k++) {
            float4 a0 = *(const float4*)&As[k * 132 + tr * 8];
            float4 a1 = *(const float4*)&As[k * 132 + tr * 8 + 4];
            float4 b0 = *(const float4*)&Ws[k * 132 + tc * 8];
            float4 b1 = *(const float4*)&Ws[k * 132 + tc * 8 + 4];
            float av[8] = {a0.x, a0.y, a0.z, a0.w, a1.x, a1.y, a1.z, a1.w};
            float bv[8] = {b0.x, b0.y, b0.z, b0.w, b1.x, b1.y, b1.z, b1.w};
#pragma unroll
            for (int i = 0; i < 8; i++)
#pragma unroll
                for (int j = 0; j < 8; j++) acc[i][j] += av[i] * bv[j];
        }
        __syncthreads();
    }

    // --- epilogue: per-column scale/add
    float cs[8], ca[8];
#pragma unroll
    for (int j = 0; j < 8; j++) {
        int n = tc * 8 + j;
        if (MODE == 2) {
            float s = gm[n] * rsqrtf(rv[n] + BN_EPS);
            cs[j] = s;
            ca[j] = (bias[n] - rm[n]) * s + bt[n];
        } else {
            cs[j] = 1.f;
            ca[j] = bias[n];
        }
    }
#pragma unroll
    for (int i = 0; i < 8; i++) {
        int r = row0 + tr * 8 + i;
        if (r < M) {
            float o[8];
#pragma unroll
            for (int j = 0; j < 8; j++) {
                float v = acc[i][j] * cs[j] + ca[j];
                if (MODE >= 1) v = fmaxf(v, 0.f);
                o[j] = v;
            }
            *(float4*)(C + (size_t)r * 128 + tc * 8)     = make_float4(o[0], o[1], o[2], o[3]);
            *(float4*)(C + (size_t)r * 128 + tc * 8 + 4) = make_float4(o[4], o[5], o[6], o[7]);
        }
    }
}

// ----------------------------------------------------------------- pooling
__global__ __launch_bounds__(128) void pool_kernel(const float* __restrict__ x1,
                                                   const float* __restrict__ x2,
                                                   const float* __restrict__ x3,
                                                   const int* __restrict__ batch,
                                                   float* __restrict__ pooled, int n) {
    int g = blockIdx.x;
    int t = threadIdx.x;
    int lo = 0, hi = n;
    while (lo < hi) { int mid = (lo + hi) >> 1; if (batch[mid] < g) lo = mid + 1; else hi = mid; }
    int start = lo;
    int lo2 = start, hi2 = n;
    while (lo2 < hi2) { int mid = (lo2 + hi2) >> 1; if (batch[mid] < g + 1) lo2 = mid + 1; else hi2 = mid; }
    int end = lo2;

    float s1 = 0.f, s2 = 0.f, s3 = 0.f;
    for (int i = start; i < end; i++) {
        s1 += x1[(size_t)i * 128 + t];
        s2 += x2[(size_t)i * 128 + t];
        s3 += x3[(size_t)i * 128 + t];
    }
    int c = end - start;
    float inv = 1.0f / (c > 0 ? (float)c : 1.0f);
    pooled[g * 384 + t]       = s1 * inv;
    pooled[g * 384 + 128 + t] = s2 * inv;
    pooled[g * 384 + 256 + t] = s3 * inv;
}

__global__ __launch_bounds__(128) void final_kernel(const float* __restrict__ pooled,
                                                    const float* __restrict__ W,
                                                    const float* __restrict__ b,
                                                    float* __restrict__ out) {
    __shared__ float ps[384];
    int g = blockIdx.x, t = threadIdx.x;
    for (int i = t; i < 384; i += 128) ps[i] = pooled[g * 384 + i];
    __syncthreads();
    float acc = b[t];
#pragma unroll 4
    for (int k = 0; k < 384; k++) acc += ps[k] * W[k * 128 + t];
    out[g * 128 + t] = acc;
}

// ------------------------------------------------------------------ launch
extern "C" void kernel_launch(void* const* d_in, const int* in_sizes, int n_in,
                              void* d_out, int out_size, void* d_ws, size_t ws_size,
                              hipStream_t stream) {
    const float* x     = (const float*)d_in[0];
    const int*   edge  = (const int*)d_in[1];
    const int*   batch = (const int*)d_in[2];
    const float* p[32];
    for (int i = 0; i < n_in && i < 32; i++) p[i] = (const float*)d_in[i];
    const float* lin_W = p[27];
    const float* lin_b = p[28];

    char* w = (char*)d_ws;
    auto alloc = [&](size_t bytes) { void* r = (void*)w; w += (bytes + 255) & ~(size_t)255; return r; };
    float* tmp    = (float*)alloc((size_t)NNODES * 128 * 4);
    float* x1     = (float*)alloc((size_t)NNODES * 128 * 4);
    float* x2b    = (float*)alloc((size_t)NNODES * 128 * 4);
    float* x3b    = (float*)alloc((size_t)NNODES * 128 * 4);
    float* pooled = (float*)alloc((size_t)NGRAPHS * 384 * 4);
    int* counts   = (int*)alloc((size_t)NNODES * 4);
    int* cursor   = (int*)alloc((size_t)NNODES * 4);
    int* row_ptr  = (int*)alloc((size_t)(NNODES + 1) * 4);
    int* esrc     = (int*)alloc((size_t)NEDGES * 4);
    int* partials = (int*)alloc(256 * 4);

    const int* src = edge;
    const int* dst = edge + NEDGES;

    // --- CSR build (once per call, reused by all 3 layers)
    hipMemsetAsync(counts, 0, (size_t)NNODES * 4, stream);
    hist_kernel<<<(NEDGES + 255) / 256, 256, 0, stream>>>(dst, counts, NEDGES);
    int nb = (NNODES + 255) / 256;  // 196
    scan1_kernel<<<nb, 256, 0, stream>>>(counts, partials, NNODES);
    scan2_kernel<<<1, 256, 0, stream>>>(partials, nb, row_ptr, NEDGES);
    scan3_kernel<<<nb, 256, 0, stream>>>(counts, partials, row_ptr, cursor, NNODES);
    scatter_kernel<<<(NEDGES + 255) / 256, 256, 0, stream>>>(src, dst, cursor, esrc, NEDGES);

    // --- 3 GIN layers
    const float* xin = x;
    float* outs[3] = {x1, x2b, x3b};
    int gemm_grid = (NNODES + 127) / 128;  // 391
    for (int li = 0; li < 3; li++) {
        const float* W1 = p[3 + 8 * li];
        const float* b1 = p[4 + 8 * li];
        const float* gm = p[5 + 8 * li];
        const float* bt = p[6 + 8 * li];
        const float* rm = p[7 + 8 * li];
        const float* rv = p[8 + 8 * li];
        const float* W2 = p[9 + 8 * li];
        const float* b2 = p[10 + 8 * li];

        agg_kernel<<<(NNODES * 64 + 255) / 256, 256, 0, stream>>>(xin, row_ptr, esrc, tmp, NNODES);
        gemm_kernel<2><<<gemm_grid, 256, 0, stream>>>(tmp, tmp, W1, b1, gm, bt, rm, rv, NNODES);
        if (li < 2)
            gemm_kernel<1><<<gemm_grid, 256, 0, stream>>>(tmp, outs[li], W2, b2,
                                                          nullptr, nullptr, nullptr, nullptr, NNODES);
        else
            gemm_kernel<0><<<gemm_grid, 256, 0, stream>>>(tmp, outs[li], W2, b2,
                                                          nullptr, nullptr, nullptr, nullptr, NNODES);
        xin = outs[li];
    }

    // --- JK-concat mean pool + final linear
    pool_kernel<<<NGRAPHS, 128, 0, stream>>>(x1, x2b, x3b, batch, pooled, NNODES);
    final_kernel<<<NGRAPHS, 128, 0, stream>>>(pooled, lin_W, lin_b, (float*)d_out);
}

// Round 3
// 499.938 us; speedup vs baseline: 1.3615x; 1.2056x over previous
//
#include <hip/hip_runtime.h>
#include <hip/hip_bf16.h>

#define NNODES 50000
#define NEDGES 600000
#define CH 128
#define NGRAPHS 512
#define BN_EPS 1e-5f

typedef short bf16x8 __attribute__((ext_vector_type(8)));
typedef float f32x4 __attribute__((ext_vector_type(4)));

// split fp32 -> hi/lo bf16 (RNE); hi+lo carries ~16 mantissa bits
__device__ __forceinline__ void bf_split(float x, ushort& h, ushort& l) {
    __hip_bfloat16 bh = __float2bfloat16(x);
    float r = x - __bfloat162float(bh);
    __hip_bfloat16 bl = __float2bfloat16(r);
    h = __builtin_bit_cast(ushort, bh);
    l = __builtin_bit_cast(ushort, bl);
}

// ---------------------------------------------------------------- CSR build
__global__ __launch_bounds__(256) void hist_kernel(const int* __restrict__ dst,
                                                   int* __restrict__ counts, int E) {
    int i = blockIdx.x * 256 + threadIdx.x;
    if (i < E) atomicAdd(&counts[dst[i]], 1);
}

__global__ __launch_bounds__(256) void scan1_kernel(const int* __restrict__ counts,
                                                    int* __restrict__ partials, int n) {
    __shared__ int s[256];
    int i = blockIdx.x * 256 + threadIdx.x;
    int v = (i < n) ? counts[i] : 0;
    s[threadIdx.x] = v;
    __syncthreads();
    for (int off = 128; off > 0; off >>= 1) {
        if (threadIdx.x < off) s[threadIdx.x] += s[threadIdx.x + off];
        __syncthreads();
    }
    if (threadIdx.x == 0) partials[blockIdx.x] = s[0];
}

__global__ __launch_bounds__(256) void scan2_kernel(int* __restrict__ partials, int nb,
                                                    int* __restrict__ row_ptr, int total) {
    __shared__ int s[256];
    int t = threadIdx.x;
    int v = (t < nb) ? partials[t] : 0;
    s[t] = v;
    __syncthreads();
    for (int off = 1; off < 256; off <<= 1) {
        int nv = (t >= off) ? s[t - off] : 0;
        __syncthreads();
        s[t] += nv;
        __syncthreads();
    }
    if (t < nb) partials[t] = s[t] - v;   // exclusive
    if (t == 0) row_ptr[NNODES] = total;
}

__global__ __launch_bounds__(256) void scan3_kernel(const int* __restrict__ counts,
                                                    const int* __restrict__ partials,
                                                    int* __restrict__ row_ptr,
                                                    int* __restrict__ cursor, int n) {
    __shared__ int s[256];
    int i = blockIdx.x * 256 + threadIdx.x;
    int v = (i < n) ? counts[i] : 0;
    s[threadIdx.x] = v;
    __syncthreads();
    for (int off = 1; off < 256; off <<= 1) {
        int nv = (threadIdx.x >= (unsigned)off) ? s[threadIdx.x - off] : 0;
        __syncthreads();
        s[threadIdx.x] += nv;
        __syncthreads();
    }
    if (i < n) {
        int ex = partials[blockIdx.x] + s[threadIdx.x] - v;  // exclusive
        row_ptr[i] = ex;
        cursor[i] = ex;
    }
}

__global__ __launch_bounds__(256) void scatter_kernel(const int* __restrict__ src,
                                                      const int* __restrict__ dst,
                                                      int* __restrict__ cursor,
                                                      int* __restrict__ esrc, int E) {
    int i = blockIdx.x * 256 + threadIdx.x;
    if (i < E) {
        int p = atomicAdd(&cursor[dst[i]], 1);
        esrc[p] = src[i];
    }
}

// ---------------------------------------------------------------- W prep
// For each of 6 weight matrices W[k][n] fp32 -> transposed bf16 hi/lo [n][k].
__global__ __launch_bounds__(256) void wsplit_kernel(
    const float* W0, const float* W1, const float* W2, const float* W3,
    const float* W4, const float* W5, ushort* __restrict__ hi, ushort* __restrict__ lo) {
    const float* Ws[6] = {W0, W1, W2, W3, W4, W5};
    const float* W = Ws[blockIdx.y];
    ushort* h = hi + (size_t)blockIdx.y * 16384;
    ushort* l = lo + (size_t)blockIdx.y * 16384;
#pragma unroll
    for (int i = 0; i < 4; i++) {
        int idx = blockIdx.x * 1024 + i * 256 + threadIdx.x;
        int k = idx >> 7, n = idx & 127;
        ushort hh, ll;
        bf_split(W[idx], hh, ll);
        h[n * 128 + k] = hh;
        l[n * 128 + k] = ll;
    }
}

// ------------------------------------------------------------- aggregation
// 2 nodes per wave; 32 lanes x float4 per node row (512B/row). Unroll-4 keeps
// 4KB of row loads in flight per wave (R2 was latency-bound at 45% HBM).
__global__ __launch_bounds__(256) void agg_kernel(const float* __restrict__ x,
                                                  const int* __restrict__ rp,
                                                  const int* __restrict__ esrc,
                                                  float* __restrict__ out, int n) {
    int wid  = (blockIdx.x * 256 + threadIdx.x) >> 6;
    int lane = threadIdx.x & 63;
    int node = wid * 2 + (lane >> 5);
    int l = lane & 31;
    if (node >= n) return;
    const float4* x4 = (const float4*)x;
    float4 acc = x4[(size_t)node * 32 + l];   // self term (eps=0)
    int beg = rp[node], end = rp[node + 1];
    int e = beg;
    for (; e + 4 <= end; e += 4) {
        int s0 = esrc[e], s1 = esrc[e + 1], s2 = esrc[e + 2], s3 = esrc[e + 3];
        float4 v0 = x4[(size_t)s0 * 32 + l];
        float4 v1 = x4[(size_t)s1 * 32 + l];
        float4 v2 = x4[(size_t)s2 * 32 + l];
        float4 v3 = x4[(size_t)s3 * 32 + l];
        acc.x += (v0.x + v1.x) + (v2.x + v3.x);
        acc.y += (v0.y + v1.y) + (v2.y + v3.y);
        acc.z += (v0.z + v1.z) + (v2.z + v3.z);
        acc.w += (v0.w + v1.w) + (v2.w + v3.w);
    }
    for (; e < end; e++) {
        int s = esrc[e];
        float4 v = x4[(size_t)s * 32 + l];
        acc.x += v.x; acc.y += v.y; acc.z += v.z; acc.w += v.w;
    }
    ((float4*)out)[(size_t)node * 32 + l] = acc;
}

// ------------------------------------------------------------------- GEMM
// C[M,128] = A[M,128] @ W[128,128] via split-bf16 MFMA:
//   A@W ~= Ahi@Whi + Ahi@Wlo + Alo@Whi   (fp32-like accuracy)
// Block: 256 thr (4 waves), tile 128x128; wave tile 64x64 = 4x4 of
// mfma_f32_16x16x32_bf16 tiles. K staged in 4 chunks of 32, bf16 in LDS with
// +8 pad (2-way bank alias = free). Next chunk prefetched to regs across the
// barrier. LDS 40KB. In-place safe (A reads precede all stores; blocks own
// disjoint row ranges).
#define KPAD 40
template <int MODE>  // 0:+bias  1:+bias,relu  2:+bias,BN,relu
__global__ __launch_bounds__(256, 2) void gemm_kernel(
    const float* __restrict__ A, float* __restrict__ C,
    const ushort* __restrict__ Wthi, const ushort* __restrict__ Wtlo,  // [n][k] bf16
    const float* __restrict__ bias,
    const float* __restrict__ gm, const float* __restrict__ bt,
    const float* __restrict__ rm, const float* __restrict__ rv, int M) {
    __shared__ __align__(16) ushort As_hi[128 * KPAD];
    __shared__ __align__(16) ushort As_lo[128 * KPAD];
    __shared__ __align__(16) ushort Ws_hi[128 * KPAD];
    __shared__ __align__(16) ushort Ws_lo[128 * KPAD];
    const int t = threadIdx.x;
    const int lane = t & 63;
    const int wv = t >> 6;
    const int wr = wv >> 1, wc = wv & 1;
    const int row0 = blockIdx.x * 128;
    const int g = lane >> 4, c = lane & 15;

    f32x4 acc[4][4];
#pragma unroll
    for (int i = 0; i < 4; i++)
#pragma unroll
        for (int j = 0; j < 4; j++) acc[i][j] = (f32x4){0.f, 0.f, 0.f, 0.f};

    float4 pa[4];
    ulonglong2 pwh[2], pwl[2];

    auto load_chunk = [&](int kb) {
#pragma unroll
        for (int i = 0; i < 4; i++) {
            int u = t + i * 256;            // 1024 float4 units: 8 per row
            int m = u >> 3, k4 = (u & 7) * 4;
            int r = row0 + m;
            pa[i] = (r < M) ? *(const float4*)(A + (size_t)r * 128 + kb * 32 + k4)
                            : make_float4(0.f, 0.f, 0.f, 0.f);
        }
#pragma unroll
        for (int i = 0; i < 2; i++) {
            int u = t + i * 256;            // 512 16B units: 4 per n-row
            int n = u >> 2, kc = (u & 3) * 8;
            pwh[i] = *(const ulonglong2*)(Wthi + n * 128 + kb * 32 + kc);
            pwl[i] = *(const ulonglong2*)(Wtlo + n * 128 + kb * 32 + kc);
        }
    };
    auto store_chunk = [&]() {
#pragma unroll
        for (int i = 0; i < 4; i++) {
            int u = t + i * 256;
            int m = u >> 3, k4 = (u & 7) * 4;
            float4 v = pa[i];
            ushort4 h, l;
            bf_split(v.x, h.x, l.x);
            bf_split(v.y, h.y, l.y);
            bf_split(v.z, h.z, l.z);
            bf_split(v.w, h.w, l.w);
            *(ushort4*)&As_hi[m * KPAD + k4] = h;
            *(ushort4*)&As_lo[m * KPAD + k4] = l;
        }
#pragma unroll
        for (int i = 0; i < 2; i++) {
            int u = t + i * 256;
            int n = u >> 2, kc = (u & 3) * 8;
            *(ulonglong2*)&Ws_hi[n * KPAD + kc] = pwh[i];
            *(ulonglong2*)&Ws_lo[n * KPAD + kc] = pwl[i];
        }
    };

    load_chunk(0);
    for (int kb = 0; kb < 4; kb++) {
        store_chunk();
        __syncthreads();
        if (kb < 3) load_chunk(kb + 1);   // global loads in flight over compute

        bf16x8 ah[4], al[4], bh[4], bl[4];
#pragma unroll
        for (int rt = 0; rt < 4; rt++) {
            int off = (wr * 64 + rt * 16 + c) * KPAD + g * 8;
            ah[rt] = *(bf16x8*)&As_hi[off];
            al[rt] = *(bf16x8*)&As_lo[off];
        }
#pragma unroll
        for (int ct = 0; ct < 4; ct++) {
            int off = (wc * 64 + ct * 16 + c) * KPAD + g * 8;
            bh[ct] = *(bf16x8*)&Ws_hi[off];
            bl[ct] = *(bf16x8*)&Ws_lo[off];
        }
#pragma unroll
        for (int rt = 0; rt < 4; rt++)
#pragma unroll
            for (int ct = 0; ct < 4; ct++) {
                acc[rt][ct] = __builtin_amdgcn_mfma_f32_16x16x32_bf16(ah[rt], bh[ct], acc[rt][ct], 0, 0, 0);
                acc[rt][ct] = __builtin_amdgcn_mfma_f32_16x16x32_bf16(ah[rt], bl[ct], acc[rt][ct], 0, 0, 0);
                acc[rt][ct] = __builtin_amdgcn_mfma_f32_16x16x32_bf16(al[rt], bh[ct], acc[rt][ct], 0, 0, 0);
            }
        __syncthreads();
    }

    // epilogue: C/D layout col=lane&15, row=(lane>>4)*4+reg (verified m89/m91)
    float cs[4], ca[4];
#pragma unroll
    for (int ct = 0; ct < 4; ct++) {
        int n = wc * 64 + ct * 16 + c;
        if (MODE == 2) {
            float s = gm[n] * rsqrtf(rv[n] + BN_EPS);
            cs[ct] = s;
            ca[ct] = (bias[n] - rm[n]) * s + bt[n];
        } else {
            cs[ct] = 1.f;
            ca[ct] = bias[n];
        }
    }
#pragma unroll
    for (int rt = 0; rt < 4; rt++) {
#pragma unroll
        for (int r = 0; r < 4; r++) {
            int row = row0 + wr * 64 + rt * 16 + g * 4 + r;
            if (row < M) {
#pragma unroll
                for (int ct = 0; ct < 4; ct++) {
                    int col = wc * 64 + ct * 16 + c;
                    float v = acc[rt][ct][r] * cs[ct] + ca[ct];
                    if (MODE >= 1) v = fmaxf(v, 0.f);
                    C[(size_t)row * 128 + col] = v;
                }
            }
        }
    }
}

// ----------------------------------------------------------------- pooling
// node-parallel: 391 blocks x 384 thr; run-length accumulate (batch sorted),
// one atomicAdd per (graph-boundary, channel). R2 version was 1 block/graph
// at 8% occupancy, 47us.
__global__ __launch_bounds__(384) void pool_kernel(const float* __restrict__ x1,
                                                   const float* __restrict__ x2,
                                                   const float* __restrict__ x3,
                                                   const int* __restrict__ batch,
                                                   float* __restrict__ pooled, int n) {
    __shared__ int bs[128];
    int b0 = blockIdx.x * 128;
    int t = threadIdx.x;
    int rows = n - b0; if (rows > 128) rows = 128;
    for (int i = t; i < rows; i += 384) bs[i] = batch[b0 + i];
    __syncthreads();
    const float* src = (t < 128) ? x1 : ((t < 256) ? x2 : x3);
    int ch = t & 127;
    int gcur = bs[0];
    float acc = 0.f;
#pragma unroll 4
    for (int r = 0; r < rows; r++) {
        int gg = bs[r];
        if (gg != gcur) {                       // block-uniform branch
            atomicAdd(&pooled[gcur * 384 + t], acc);
            acc = 0.f;
            gcur = gg;
        }
        acc += src[(size_t)(b0 + r) * 128 + ch];
    }
    atomicAdd(&pooled[gcur * 384 + t], acc);
}

__global__ __launch_bounds__(128) void final_kernel(const float* __restrict__ pooled,
                                                    const int* __restrict__ batch,
                                                    const float* __restrict__ W,
                                                    const float* __restrict__ b,
                                                    float* __restrict__ out, int n) {
    __shared__ float ps[384];
    int gph = blockIdx.x, t = threadIdx.x;
    int lo1 = 0, hi1 = n;
    while (lo1 < hi1) { int mid = (lo1 + hi1) >> 1; if (batch[mid] < gph) lo1 = mid + 1; else hi1 = mid; }
    int start = lo1;
    int lo2 = start, hi2 = n;
    while (lo2 < hi2) { int mid = (lo2 + hi2) >> 1; if (batch[mid] < gph + 1) lo2 = mid + 1; else hi2 = mid; }
    int cnt = lo2 - start;
    float inv = 1.f / (float)(cnt > 0 ? cnt : 1);
    for (int i = t; i < 384; i += 128) ps[i] = pooled[gph * 384 + i] * inv;
    __syncthreads();
    float acc = b[t];
#pragma unroll 8
    for (int k = 0; k < 384; k++) acc += ps[k] * W[k * 128 + t];
    out[gph * 128 + t] = acc;
}

// ------------------------------------------------------------------ launch
extern "C" void kernel_launch(void* const* d_in, const int* in_sizes, int n_in,
                              void* d_out, int out_size, void* d_ws, size_t ws_size,
                              hipStream_t stream) {
    const float* x     = (const float*)d_in[0];
    const int*   edge  = (const int*)d_in[1];
    const int*   batch = (const int*)d_in[2];
    const float* p[32];
    for (int i = 0; i < n_in && i < 32; i++) p[i] = (const float*)d_in[i];
    const float* lin_W = p[27];
    const float* lin_b = p[28];

    char* w = (char*)d_ws;
    auto alloc = [&](size_t bytes) { void* r = (void*)w; w += (bytes + 255) & ~(size_t)255; return r; };
    float* tmp    = (float*)alloc((size_t)NNODES * 128 * 4);
    float* x1     = (float*)alloc((size_t)NNODES * 128 * 4);
    float* x2b    = (float*)alloc((size_t)NNODES * 128 * 4);
    float* x3b    = (float*)alloc((size_t)NNODES * 128 * 4);
    float* pooled = (float*)alloc((size_t)NGRAPHS * 384 * 4);
    int* counts   = (int*)alloc((size_t)NNODES * 4);
    int* cursor   = (int*)alloc((size_t)NNODES * 4);
    int* row_ptr  = (int*)alloc((size_t)(NNODES + 1) * 4);
    int* esrc     = (int*)alloc((size_t)NEDGES * 4);
    int* partials = (int*)alloc(256 * 4);
    ushort* wt_hi = (ushort*)alloc((size_t)6 * 16384 * 2);
    ushort* wt_lo = (ushort*)alloc((size_t)6 * 16384 * 2);

    const int* src = edge;
    const int* dst = edge + NEDGES;

    // --- weight split/transpose (6 matrices: W1,W2 per layer)
    wsplit_kernel<<<dim3(16, 6), 256, 0, stream>>>(p[3], p[9], p[11], p[17], p[19], p[25],
                                                   wt_hi, wt_lo);

    // --- CSR build (reused by all 3 layers)
    hipMemsetAsync(counts, 0, (size_t)NNODES * 4, stream);
    hipMemsetAsync(pooled, 0, (size_t)NGRAPHS * 384 * 4, stream);
    hist_kernel<<<(NEDGES + 255) / 256, 256, 0, stream>>>(dst, counts, NEDGES);
    int nb = (NNODES + 255) / 256;  // 196
    scan1_kernel<<<nb, 256, 0, stream>>>(counts, partials, NNODES);
    scan2_kernel<<<1, 256, 0, stream>>>(partials, nb, row_ptr, NEDGES);
    scan3_kernel<<<nb, 256, 0, stream>>>(counts, partials, row_ptr, cursor, NNODES);
    scatter_kernel<<<(NEDGES + 255) / 256, 256, 0, stream>>>(src, dst, cursor, esrc, NEDGES);

    // --- 3 GIN layers
    const float* xin = x;
    float* outs[3] = {x1, x2b, x3b};
    int gemm_grid = (NNODES + 127) / 128;  // 391
    int agg_grid = ((NNODES + 1) / 2 * 64 + 255) / 256;
    for (int li = 0; li < 3; li++) {
        const float* b1 = p[4 + 8 * li];
        const float* gm = p[5 + 8 * li];
        const float* bt = p[6 + 8 * li];
        const float* rm = p[7 + 8 * li];
        const float* rv = p[8 + 8 * li];
        const float* b2 = p[10 + 8 * li];
        const ushort* w1h = wt_hi + (size_t)(2 * li) * 16384;
        const ushort* w1l = wt_lo + (size_t)(2 * li) * 16384;
        const ushort* w2h = wt_hi + (size_t)(2 * li + 1) * 16384;
        const ushort* w2l = wt_lo + (size_t)(2 * li + 1) * 16384;

        agg_kernel<<<agg_grid, 256, 0, stream>>>(xin, row_ptr, esrc, tmp, NNODES);
        gemm_kernel<2><<<gemm_grid, 256, 0, stream>>>(tmp, tmp, w1h, w1l, b1, gm, bt, rm, rv, NNODES);
        if (li < 2)
            gemm_kernel<1><<<gemm_grid, 256, 0, stream>>>(tmp, outs[li], w2h, w2l, b2,
                                                          nullptr, nullptr, nullptr, nullptr, NNODES);
        else
            gemm_kernel<0><<<gemm_grid, 256, 0, stream>>>(tmp, outs[li], w2h, w2l, b2,
                                                          nullptr, nullptr, nullptr, nullptr, NNODES);
        xin = outs[li];
    }

    // --- JK-concat mean pool + final linear
    pool_kernel<<<(NNODES + 127) / 128, 384, 0, stream>>>(x1, x2b, x3b, batch, pooled, NNODES);
    final_kernel<<<NGRAPHS, 128, 0, stream>>>(pooled, batch, lin_W, lin_b, (float*)d_out, NNODES);
}

// Round 4
// 493.469 us; speedup vs baseline: 1.3794x; 1.0131x over previous
//
#include <hip/hip_runtime.h>
#include <hip/hip_bf16.h>

#define NNODES 50000
#define NEDGES 600000
#define NGRAPHS 512
#define BN_EPS 1e-5f

typedef short bf16x8 __attribute__((ext_vector_type(8)));
typedef float f32x4 __attribute__((ext_vector_type(4)));

// split fp32 -> hi/lo bf16 (RNE); hi+lo carries ~16 mantissa bits
__device__ __forceinline__ void bf_split(float x, ushort& h, ushort& l) {
    __hip_bfloat16 bh = __float2bfloat16(x);
    float r = x - __bfloat162float(bh);
    __hip_bfloat16 bl = __float2bfloat16(r);
    h = __builtin_bit_cast(ushort, bh);
    l = __builtin_bit_cast(ushort, bl);
}

// ---------------------------------------------------------------- CSR build
__global__ __launch_bounds__(256) void hist_kernel(const int* __restrict__ dst,
                                                   int* __restrict__ counts, int E) {
    int i = blockIdx.x * 256 + threadIdx.x;
    if (i < E) atomicAdd(&counts[dst[i]], 1);
}

__global__ __launch_bounds__(256) void scan1_kernel(const int* __restrict__ counts,
                                                    int* __restrict__ partials, int n) {
    __shared__ int s[256];
    int i = blockIdx.x * 256 + threadIdx.x;
    int v = (i < n) ? counts[i] : 0;
    s[threadIdx.x] = v;
    __syncthreads();
    for (int off = 128; off > 0; off >>= 1) {
        if (threadIdx.x < off) s[threadIdx.x] += s[threadIdx.x + off];
        __syncthreads();
    }
    if (threadIdx.x == 0) partials[blockIdx.x] = s[0];
}

__global__ __launch_bounds__(256) void scan2_kernel(int* __restrict__ partials, int nb,
                                                    int* __restrict__ row_ptr, int total) {
    __shared__ int s[256];
    int t = threadIdx.x;
    int v = (t < nb) ? partials[t] : 0;
    s[t] = v;
    __syncthreads();
    for (int off = 1; off < 256; off <<= 1) {
        int nv = (t >= off) ? s[t - off] : 0;
        __syncthreads();
        s[t] += nv;
        __syncthreads();
    }
    if (t < nb) partials[t] = s[t] - v;   // exclusive
    if (t == 0) row_ptr[NNODES] = total;
}

__global__ __launch_bounds__(256) void scan3_kernel(const int* __restrict__ counts,
                                                    const int* __restrict__ partials,
                                                    int* __restrict__ row_ptr,
                                                    int* __restrict__ cursor, int n) {
    __shared__ int s[256];
    int i = blockIdx.x * 256 + threadIdx.x;
    int v = (i < n) ? counts[i] : 0;
    s[threadIdx.x] = v;
    __syncthreads();
    for (int off = 1; off < 256; off <<= 1) {
        int nv = (threadIdx.x >= (unsigned)off) ? s[threadIdx.x - off] : 0;
        __syncthreads();
        s[threadIdx.x] += nv;
        __syncthreads();
    }
    if (i < n) {
        int ex = partials[blockIdx.x] + s[threadIdx.x] - v;  // exclusive
        row_ptr[i] = ex;
        cursor[i] = ex;
    }
}

__global__ __launch_bounds__(256) void scatter_kernel(const int* __restrict__ src,
                                                      const int* __restrict__ dst,
                                                      int* __restrict__ cursor,
                                                      int* __restrict__ esrc, int E) {
    int i = blockIdx.x * 256 + threadIdx.x;
    if (i < E) {
        int p = atomicAdd(&cursor[dst[i]], 1);
        esrc[p] = src[i];
    }
}

// ---------------------------------------------------------------- W prep
// W[k][n] fp32 -> transposed bf16 hi/lo planes [n][k]. Thread maps k-consecutive
// so the 2B plane writes coalesce; scattered reads ride L2.
__global__ __launch_bounds__(256) void wsplit_kernel(
    const float* W0, const float* W1, const float* W2, const float* W3,
    const float* W4, const float* W5, ushort* __restrict__ hi, ushort* __restrict__ lo) {
    const float* Ws[6] = {W0, W1, W2, W3, W4, W5};
    const float* W = Ws[blockIdx.y];
    ushort* h = hi + (size_t)blockIdx.y * 16384;
    ushort* l = lo + (size_t)blockIdx.y * 16384;
#pragma unroll
    for (int i = 0; i < 4; i++) {
        int idx = blockIdx.x * 1024 + i * 256 + threadIdx.x;
        int n = idx >> 7, k = idx & 127;
        ushort hh, ll;
        bf_split(W[k * 128 + n], hh, ll);
        h[n * 128 + k] = hh;
        l[n * 128 + k] = ll;
    }
}

// ------------------------------------------------------------- aggregation
// 2 nodes/wave, 32 lanes x float4. fp32 gather + exact fp32 sum, output is
// pre-split hi/lo bf16 planes (removes all bf_split work from the GEMMs).
// Unroll-8 keeps 8 row-loads in flight (R3 was latency-bound: VALU 10%, hbm 46%).
__global__ __launch_bounds__(256) void agg_kernel(const float* __restrict__ x,
                                                  const int* __restrict__ rp,
                                                  const int* __restrict__ esrc,
                                                  ushort* __restrict__ ohi,
                                                  ushort* __restrict__ olo, int n) {
    int wid  = (blockIdx.x * 256 + threadIdx.x) >> 6;
    int lane = threadIdx.x & 63;
    int node = wid * 2 + (lane >> 5);
    int q = lane & 31;
    if (node >= n) return;
    const float4* x4 = (const float4*)x;
    float4 acc = x4[(size_t)node * 32 + q];   // self term (eps=0)
    int beg = rp[node], end = rp[node + 1];
    int e = beg;
    for (; e + 8 <= end; e += 8) {
        int i0 = esrc[e],     i1 = esrc[e + 1], i2 = esrc[e + 2], i3 = esrc[e + 3];
        int i4 = esrc[e + 4], i5 = esrc[e + 5], i6 = esrc[e + 6], i7 = esrc[e + 7];
        float4 v0 = x4[(size_t)i0 * 32 + q];
        float4 v1 = x4[(size_t)i1 * 32 + q];
        float4 v2 = x4[(size_t)i2 * 32 + q];
        float4 v3 = x4[(size_t)i3 * 32 + q];
        float4 v4 = x4[(size_t)i4 * 32 + q];
        float4 v5 = x4[(size_t)i5 * 32 + q];
        float4 v6 = x4[(size_t)i6 * 32 + q];
        float4 v7 = x4[(size_t)i7 * 32 + q];
        acc.x += ((v0.x + v1.x) + (v2.x + v3.x)) + ((v4.x + v5.x) + (v6.x + v7.x));
        acc.y += ((v0.y + v1.y) + (v2.y + v3.y)) + ((v4.y + v5.y) + (v6.y + v7.y));
        acc.z += ((v0.z + v1.z) + (v2.z + v3.z)) + ((v4.z + v5.z) + (v6.z + v7.z));
        acc.w += ((v0.w + v1.w) + (v2.w + v3.w)) + ((v4.w + v5.w) + (v6.w + v7.w));
    }
    for (; e + 2 <= end; e += 2) {
        int i0 = esrc[e], i1 = esrc[e + 1];
        float4 v0 = x4[(size_t)i0 * 32 + q];
        float4 v1 = x4[(size_t)i1 * 32 + q];
        acc.x += v0.x + v1.x; acc.y += v0.y + v1.y;
        acc.z += v0.z + v1.z; acc.w += v0.w + v1.w;
    }
    for (; e < end; e++) {
        int i0 = esrc[e];
        float4 v = x4[(size_t)i0 * 32 + q];
        acc.x += v.x; acc.y += v.y; acc.z += v.z; acc.w += v.w;
    }
    ushort4 hh, ll;
    bf_split(acc.x, hh.x, ll.x);
    bf_split(acc.y, hh.y, ll.y);
    bf_split(acc.z, hh.z, ll.z);
    bf_split(acc.w, hh.w, ll.w);
    *(ushort4*)(ohi + (size_t)node * 128 + q * 4) = hh;
    *(ushort4*)(olo + (size_t)node * 128 + q * 4) = ll;
}

// ------------------------------------------------------------------- GEMM
// C = A @ W via split-bf16 MFMA (Ahi@Whi + Ahi@Wlo + Alo@Whi), A arrives as
// pre-split planes. 256 thr, tile 128x128; wave tile 64x64 = 4x4 of 16x16x32.
// A planes double-buffered in LDS [2][2][128*32] ushort (32KB), ONE barrier
// per kb; staging is a pure 4x16B copy per thread. W fragments read directly
// from global (L1/L2-hot, no LDS round-trip). Unpadded [m][32] layout: the
// fragment-read pattern lands 8 accesses/bank = wave64 minimum (conflict-free).
// MODE 2: BN+relu -> hi/lo planes out.  MODE 1: relu -> fp32.  MODE 0: fp32.
template <int MODE>
__global__ __launch_bounds__(256, 2) void gemm_kernel(
    const ushort* __restrict__ Ahi, const ushort* __restrict__ Alo,
    const ushort* __restrict__ Whi, const ushort* __restrict__ Wlo,  // [n][k]
    float* __restrict__ Cf, ushort* __restrict__ Chi, ushort* __restrict__ Clo,
    const float* __restrict__ bias, const float* __restrict__ gm,
    const float* __restrict__ bt, const float* __restrict__ rm,
    const float* __restrict__ rv, int M) {
    __shared__ __align__(16) ushort As[2][2][128 * 32];   // [buf][hi/lo][m][k]
    const int t = threadIdx.x;
    const int lane = t & 63;
    const int wv = t >> 6;
    const int wr = wv >> 1, wc = wv & 1;
    const int row0 = blockIdx.x * 128;
    const int g = lane >> 4, c = lane & 15;

    // staging map: 512 16B-segs per plane per kb; this thread owns segs t, t+256
    const int m0 = t >> 2,         k80 = (t & 3) * 8;
    const int m1 = (t + 256) >> 2, k81 = (t & 3) * 8;   // (t+256)&3 == t&3
    int r0 = row0 + m0; if (r0 >= M) r0 = M - 1;
    int r1 = row0 + m1; if (r1 >= M) r1 = M - 1;
    const size_t ga0 = (size_t)r0 * 128 + k80;
    const size_t ga1 = (size_t)r1 * 128 + k81;
    const int la0 = m0 * 32 + k80, la1 = m1 * 32 + k81;

    f32x4 acc[4][4];
#pragma unroll
    for (int i = 0; i < 4; i++)
#pragma unroll
        for (int j = 0; j < 4; j++) acc[i][j] = (f32x4){0.f, 0.f, 0.f, 0.f};

    uint4 ph0 = *(const uint4*)(Ahi + ga0);
    uint4 ph1 = *(const uint4*)(Ahi + ga1);
    uint4 pl0 = *(const uint4*)(Alo + ga0);
    uint4 pl1 = *(const uint4*)(Alo + ga1);
    *(uint4*)&As[0][0][la0] = ph0;
    *(uint4*)&As[0][0][la1] = ph1;
    *(uint4*)&As[0][1][la0] = pl0;
    *(uint4*)&As[0][1][la1] = pl1;
    __syncthreads();

    int cur = 0;
    for (int kb = 0; kb < 4; kb++) {
        // W fragments straight from global (every block reads same 128KB -> L2-hot)
        bf16x8 bh[4], bl[4];
#pragma unroll
        for (int ct = 0; ct < 4; ct++) {
            const size_t wo = (size_t)(wc * 64 + ct * 16 + c) * 128 + kb * 32 + g * 8;
            bh[ct] = *(const bf16x8*)(Whi + wo);
            bl[ct] = *(const bf16x8*)(Wlo + wo);
        }
        // prefetch next A chunk (lands during MFMA section)
        if (kb < 3) {
            const size_t o = (size_t)(kb + 1) * 32;
            ph0 = *(const uint4*)(Ahi + ga0 + o);
            ph1 = *(const uint4*)(Ahi + ga1 + o);
            pl0 = *(const uint4*)(Alo + ga0 + o);
            pl1 = *(const uint4*)(Alo + ga1 + o);
        }
        bf16x8 ah[4], al[4];
#pragma unroll
        for (int rt = 0; rt < 4; rt++) {
            int off = (wr * 64 + rt * 16 + c) * 32 + g * 8;
            ah[rt] = *(bf16x8*)&As[cur][0][off];
            al[rt] = *(bf16x8*)&As[cur][1][off];
        }
#pragma unroll
        for (int rt = 0; rt < 4; rt++)
#pragma unroll
            for (int ct = 0; ct < 4; ct++) {
                acc[rt][ct] = __builtin_amdgcn_mfma_f32_16x16x32_bf16(ah[rt], bh[ct], acc[rt][ct], 0, 0, 0);
                acc[rt][ct] = __builtin_amdgcn_mfma_f32_16x16x32_bf16(ah[rt], bl[ct], acc[rt][ct], 0, 0, 0);
                acc[rt][ct] = __builtin_amdgcn_mfma_f32_16x16x32_bf16(al[rt], bh[ct], acc[rt][ct], 0, 0, 0);
            }
        if (kb < 3) {   // write prefetched chunk into the idle buffer
            *(uint4*)&As[cur ^ 1][0][la0] = ph0;
            *(uint4*)&As[cur ^ 1][0][la1] = ph1;
            *(uint4*)&As[cur ^ 1][1][la0] = pl0;
            *(uint4*)&As[cur ^ 1][1][la1] = pl1;
        }
        __syncthreads();
        cur ^= 1;
    }

    // epilogue: C/D layout col=lane&15, row=(lane>>4)*4+reg (verified m89/m91)
    float cs[4], ca[4];
#pragma unroll
    for (int ct = 0; ct < 4; ct++) {
        int n = wc * 64 + ct * 16 + c;
        if (MODE == 2) {
            float s = gm[n] * rsqrtf(rv[n] + BN_EPS);
            cs[ct] = s;
            ca[ct] = (bias[n] - rm[n]) * s + bt[n];
        } else {
            cs[ct] = 1.f;
            ca[ct] = bias[n];
        }
    }
#pragma unroll
    for (int rt = 0; rt < 4; rt++) {
#pragma unroll
        for (int r = 0; r < 4; r++) {
            int row = row0 + wr * 64 + rt * 16 + g * 4 + r;
            if (row < M) {
#pragma unroll
                for (int ct = 0; ct < 4; ct++) {
                    int col = wc * 64 + ct * 16 + c;
                    float v = acc[rt][ct][r] * cs[ct] + ca[ct];
                    if (MODE >= 1) v = fmaxf(v, 0.f);
                    if (MODE == 2) {
                        ushort hh, ll;
                        bf_split(v, hh, ll);
                        Chi[(size_t)row * 128 + col] = hh;
                        Clo[(size_t)row * 128 + col] = ll;
                    } else {
                        Cf[(size_t)row * 128 + col] = v;
                    }
                }
            }
        }
    }
}

// ----------------------------------------------------------------- pooling
__global__ __launch_bounds__(384) void pool_kernel(const float* __restrict__ x1,
                                                   const float* __restrict__ x2,
                                                   const float* __restrict__ x3,
                                                   const int* __restrict__ batch,
                                                   float* __restrict__ pooled, int n) {
    __shared__ int bs[128];
    int b0 = blockIdx.x * 128;
    int t = threadIdx.x;
    int rows = n - b0; if (rows > 128) rows = 128;
    for (int i = t; i < rows; i += 384) bs[i] = batch[b0 + i];
    __syncthreads();
    const float* src = (t < 128) ? x1 : ((t < 256) ? x2 : x3);
    int ch = t & 127;
    int gcur = bs[0];
    float acc = 0.f;
#pragma unroll 8
    for (int r = 0; r < rows; r++) {
        int gg = bs[r];
        if (gg != gcur) {                       // block-uniform branch
            atomicAdd(&pooled[gcur * 384 + t], acc);
            acc = 0.f;
            gcur = gg;
        }
        acc += src[(size_t)(b0 + r) * 128 + ch];
    }
    atomicAdd(&pooled[gcur * 384 + t], acc);
}

__global__ __launch_bounds__(128) void final_kernel(const float* __restrict__ pooled,
                                                    const int* __restrict__ batch,
                                                    const float* __restrict__ W,
                                                    const float* __restrict__ b,
                                                    float* __restrict__ out, int n) {
    __shared__ float ps[384];
    int gph = blockIdx.x, t = threadIdx.x;
    int lo1 = 0, hi1 = n;
    while (lo1 < hi1) { int mid = (lo1 + hi1) >> 1; if (batch[mid] < gph) lo1 = mid + 1; else hi1 = mid; }
    int start = lo1;
    int lo2 = start, hi2 = n;
    while (lo2 < hi2) { int mid = (lo2 + hi2) >> 1; if (batch[mid] < gph + 1) lo2 = mid + 1; else hi2 = mid; }
    int cnt = lo2 - start;
    float inv = 1.f / (float)(cnt > 0 ? cnt : 1);
    for (int i = t; i < 384; i += 128) ps[i] = pooled[gph * 384 + i] * inv;
    __syncthreads();
    float acc = b[t];
#pragma unroll 8
    for (int k = 0; k < 384; k++) acc += ps[k] * W[k * 128 + t];
    out[gph * 128 + t] = acc;
}

// ------------------------------------------------------------------ launch
extern "C" void kernel_launch(void* const* d_in, const int* in_sizes, int n_in,
                              void* d_out, int out_size, void* d_ws, size_t ws_size,
                              hipStream_t stream) {
    const float* x     = (const float*)d_in[0];
    const int*   edge  = (const int*)d_in[1];
    const int*   batch = (const int*)d_in[2];
    const float* p[32];
    for (int i = 0; i < n_in && i < 32; i++) p[i] = (const float*)d_in[i];
    const float* lin_W = p[27];
    const float* lin_b = p[28];

    char* w = (char*)d_ws;
    auto alloc = [&](size_t bytes) { void* r = (void*)w; w += (bytes + 255) & ~(size_t)255; return r; };
    const size_t PL = (size_t)NNODES * 128;          // plane elements
    ushort* thi = (ushort*)alloc(PL * 2);            // 12.8MB (exact multiple of 256)
    ushort* tlo = (ushort*)alloc(PL * 2);            // contiguous after thi
    ushort* hhi = (ushort*)alloc(PL * 2);
    ushort* hlo = (ushort*)alloc(PL * 2);
    float* x1     = (float*)alloc(PL * 4);
    float* x2b    = (float*)alloc(PL * 4);
    float* x3b    = (float*)thi;                     // alias: thi+tlo dead before x3 written
    float* pooled = (float*)alloc((size_t)NGRAPHS * 384 * 4);
    int* counts   = (int*)alloc((size_t)NNODES * 4);
    int* cursor   = (int*)alloc((size_t)NNODES * 4);
    int* row_ptr  = (int*)alloc((size_t)(NNODES + 1) * 4);
    int* esrc     = (int*)alloc((size_t)NEDGES * 4);
    int* partials = (int*)alloc(256 * 4);
    ushort* wt_hi = (ushort*)alloc((size_t)6 * 16384 * 2);
    ushort* wt_lo = (ushort*)alloc((size_t)6 * 16384 * 2);

    const int* src = edge;
    const int* dst = edge + NEDGES;

    // --- weight split/transpose (6 matrices)
    wsplit_kernel<<<dim3(16, 6), 256, 0, stream>>>(p[3], p[9], p[11], p[17], p[19], p[25],
                                                   wt_hi, wt_lo);

    // --- CSR build (reused by all 3 layers)
    hipMemsetAsync(counts, 0, (size_t)NNODES * 4, stream);
    hipMemsetAsync(pooled, 0, (size_t)NGRAPHS * 384 * 4, stream);
    hist_kernel<<<(NEDGES + 255) / 256, 256, 0, stream>>>(dst, counts, NEDGES);
    int nb = (NNODES + 255) / 256;  // 196
    scan1_kernel<<<nb, 256, 0, stream>>>(counts, partials, NNODES);
    scan2_kernel<<<1, 256, 0, stream>>>(partials, nb, row_ptr, NEDGES);
    scan3_kernel<<<nb, 256, 0, stream>>>(counts, partials, row_ptr, cursor, NNODES);
    scatter_kernel<<<(NEDGES + 255) / 256, 256, 0, stream>>>(src, dst, cursor, esrc, NEDGES);

    // --- 3 GIN layers
    int gemm_grid = (NNODES + 127) / 128;               // 391
    int agg_grid = (NNODES / 2 * 64 + 255) / 256;       // 2 nodes/wave
    const float* xin = x;
    float* fouts[3] = {x1, x2b, x3b};
    for (int li = 0; li < 3; li++) {
        const float* b1 = p[4 + 8 * li];
        const float* gm = p[5 + 8 * li];
        const float* bt = p[6 + 8 * li];
        const float* rm = p[7 + 8 * li];
        const float* rv = p[8 + 8 * li];
        const float* b2 = p[10 + 8 * li];
        const ushort* w1h = wt_hi + (size_t)(2 * li) * 16384;
        const ushort* w1l = wt_lo + (size_t)(2 * li) * 16384;
        const ushort* w2h = wt_hi + (size_t)(2 * li + 1) * 16384;
        const ushort* w2l = wt_lo + (size_t)(2 * li + 1) * 16384;

        agg_kernel<<<agg_grid, 256, 0, stream>>>(xin, row_ptr, esrc, thi, tlo, NNODES);
        gemm_kernel<2><<<gemm_grid, 256, 0, stream>>>(thi, tlo, w1h, w1l,
                                                      nullptr, hhi, hlo,
                                                      b1, gm, bt, rm, rv, NNODES);
        if (li < 2)
            gemm_kernel<1><<<gemm_grid, 256, 0, stream>>>(hhi, hlo, w2h, w2l,
                                                          fouts[li], nullptr, nullptr,
                                                          b2, nullptr, nullptr, nullptr, nullptr, NNODES);
        else
            gemm_kernel<0><<<gemm_grid, 256, 0, stream>>>(hhi, hlo, w2h, w2l,
                                                          fouts[li], nullptr, nullptr,
                                                          b2, nullptr, nullptr, nullptr, nullptr, NNODES);
        xin = fouts[li];
    }

    // --- JK-concat mean pool + final linear
    pool_kernel<<<(NNODES + 127) / 128, 384, 0, stream>>>(x1, x2b, x3b, batch, pooled, NNODES);
    final_kernel<<<NGRAPHS, 128, 0, stream>>>(pooled, batch, lin_W, lin_b, (float*)d_out, NNODES);
}

// Round 5
// 458.897 us; speedup vs baseline: 1.4833x; 1.0753x over previous
//
#include <hip/hip_runtime.h>
#include <hip/hip_bf16.h>

#define NNODES 50000
#define NEDGES 600000
#define NGRAPHS 512
#define BN_EPS 1e-5f

typedef short bf16x8 __attribute__((ext_vector_type(8)));
typedef float f32x4 __attribute__((ext_vector_type(4)));

// split fp32 -> hi/lo bf16 (RNE); hi+lo carries ~16 mantissa bits
__device__ __forceinline__ void bf_split(float x, ushort& h, ushort& l) {
    __hip_bfloat16 bh = __float2bfloat16(x);
    float r = x - __bfloat162float(bh);
    __hip_bfloat16 bl = __float2bfloat16(r);
    h = __builtin_bit_cast(ushort, bh);
    l = __builtin_bit_cast(ushort, bl);
}

// ---------------------------------------------------------------- CSR build
__global__ __launch_bounds__(256) void hist_kernel(const int* __restrict__ dst,
                                                   int* __restrict__ counts, int E) {
    int i = blockIdx.x * 256 + threadIdx.x;
    if (i < E) atomicAdd(&counts[dst[i]], 1);
}

__global__ __launch_bounds__(256) void scan1_kernel(const int* __restrict__ counts,
                                                    int* __restrict__ partials, int n) {
    __shared__ int s[256];
    int i = blockIdx.x * 256 + threadIdx.x;
    int v = (i < n) ? counts[i] : 0;
    s[threadIdx.x] = v;
    __syncthreads();
    for (int off = 128; off > 0; off >>= 1) {
        if (threadIdx.x < off) s[threadIdx.x] += s[threadIdx.x + off];
        __syncthreads();
    }
    if (threadIdx.x == 0) partials[blockIdx.x] = s[0];
}

__global__ __launch_bounds__(256) void scan2_kernel(int* __restrict__ partials, int nb,
                                                    int* __restrict__ row_ptr, int total) {
    __shared__ int s[256];
    int t = threadIdx.x;
    int v = (t < nb) ? partials[t] : 0;
    s[t] = v;
    __syncthreads();
    for (int off = 1; off < 256; off <<= 1) {
        int nv = (t >= off) ? s[t - off] : 0;
        __syncthreads();
        s[t] += nv;
        __syncthreads();
    }
    if (t < nb) partials[t] = s[t] - v;   // exclusive
    if (t == 0) row_ptr[NNODES] = total;
}

__global__ __launch_bounds__(256) void scan3_kernel(const int* __restrict__ counts,
                                                    const int* __restrict__ partials,
                                                    int* __restrict__ row_ptr,
                                                    int* __restrict__ cursor, int n) {
    __shared__ int s[256];
    int i = blockIdx.x * 256 + threadIdx.x;
    int v = (i < n) ? counts[i] : 0;
    s[threadIdx.x] = v;
    __syncthreads();
    for (int off = 1; off < 256; off <<= 1) {
        int nv = (threadIdx.x >= (unsigned)off) ? s[threadIdx.x - off] : 0;
        __syncthreads();
        s[threadIdx.x] += nv;
        __syncthreads();
    }
    if (i < n) {
        int ex = partials[blockIdx.x] + s[threadIdx.x] - v;  // exclusive
        row_ptr[i] = ex;
        cursor[i] = ex;
    }
}

__global__ __launch_bounds__(256) void scatter_kernel(const int* __restrict__ src,
                                                      const int* __restrict__ dst,
                                                      int* __restrict__ cursor,
                                                      int* __restrict__ esrc, int E) {
    int i = blockIdx.x * 256 + threadIdx.x;
    if (i < E) {
        int p = atomicAdd(&cursor[dst[i]], 1);
        esrc[p] = src[i];
    }
}

// ---------------------------------------------------------------- W prep
// W[k][n] fp32 -> transposed bf16 hi/lo planes [n][k].
__global__ __launch_bounds__(256) void wsplit_kernel(
    const float* W0, const float* W1, const float* W2, const float* W3,
    const float* W4, const float* W5, ushort* __restrict__ hi, ushort* __restrict__ lo) {
    const float* Ws[6] = {W0, W1, W2, W3, W4, W5};
    const float* W = Ws[blockIdx.y];
    ushort* h = hi + (size_t)blockIdx.y * 16384;
    ushort* l = lo + (size_t)blockIdx.y * 16384;
#pragma unroll
    for (int i = 0; i < 4; i++) {
        int idx = blockIdx.x * 1024 + i * 256 + threadIdx.x;
        int n = idx >> 7, k = idx & 127;
        ushort hh, ll;
        bf_split(W[k * 128 + n], hh, ll);
        h[n * 128 + k] = hh;
        l[n * 128 + k] = ll;
    }
}

// ------------------------------------------------------------- aggregation
// 2 nodes/wave, 32 lanes x float4; exact fp32 sum -> pre-split hi/lo planes.
__global__ __launch_bounds__(256) void agg_kernel(const float* __restrict__ x,
                                                  const int* __restrict__ rp,
                                                  const int* __restrict__ esrc,
                                                  ushort* __restrict__ ohi,
                                                  ushort* __restrict__ olo, int n) {
    int wid  = (blockIdx.x * 256 + threadIdx.x) >> 6;
    int lane = threadIdx.x & 63;
    int node = wid * 2 + (lane >> 5);
    int q = lane & 31;
    if (node >= n) return;
    const float4* x4 = (const float4*)x;
    float4 acc = x4[(size_t)node * 32 + q];   // self term (eps=0)
    int beg = rp[node], end = rp[node + 1];
    int e = beg;
    for (; e + 8 <= end; e += 8) {
        int i0 = esrc[e],     i1 = esrc[e + 1], i2 = esrc[e + 2], i3 = esrc[e + 3];
        int i4 = esrc[e + 4], i5 = esrc[e + 5], i6 = esrc[e + 6], i7 = esrc[e + 7];
        float4 v0 = x4[(size_t)i0 * 32 + q];
        float4 v1 = x4[(size_t)i1 * 32 + q];
        float4 v2 = x4[(size_t)i2 * 32 + q];
        float4 v3 = x4[(size_t)i3 * 32 + q];
        float4 v4 = x4[(size_t)i4 * 32 + q];
        float4 v5 = x4[(size_t)i5 * 32 + q];
        float4 v6 = x4[(size_t)i6 * 32 + q];
        float4 v7 = x4[(size_t)i7 * 32 + q];
        acc.x += ((v0.x + v1.x) + (v2.x + v3.x)) + ((v4.x + v5.x) + (v6.x + v7.x));
        acc.y += ((v0.y + v1.y) + (v2.y + v3.y)) + ((v4.y + v5.y) + (v6.y + v7.y));
        acc.z += ((v0.z + v1.z) + (v2.z + v3.z)) + ((v4.z + v5.z) + (v6.z + v7.z));
        acc.w += ((v0.w + v1.w) + (v2.w + v3.w)) + ((v4.w + v5.w) + (v6.w + v7.w));
    }
    for (; e + 2 <= end; e += 2) {
        int i0 = esrc[e], i1 = esrc[e + 1];
        float4 v0 = x4[(size_t)i0 * 32 + q];
        float4 v1 = x4[(size_t)i1 * 32 + q];
        acc.x += v0.x + v1.x; acc.y += v0.y + v1.y;
        acc.z += v0.z + v1.z; acc.w += v0.w + v1.w;
    }
    for (; e < end; e++) {
        int i0 = esrc[e];
        float4 v = x4[(size_t)i0 * 32 + q];
        acc.x += v.x; acc.y += v.y; acc.z += v.z; acc.w += v.w;
    }
    ushort4 hh, ll;
    bf_split(acc.x, hh.x, ll.x);
    bf_split(acc.y, hh.y, ll.y);
    bf_split(acc.z, hh.z, ll.z);
    bf_split(acc.w, hh.w, ll.w);
    *(ushort4*)(ohi + (size_t)node * 128 + q * 4) = hh;
    *(ushort4*)(olo + (size_t)node * 128 + q * 4) = ll;
}

// --------------------------------------------------------------- fused MLP
// C = act( BN_ReLU( A@W1 ) @ W2 ), all per-128-row block, split-bf16 MFMA
// (3 terms: hi@hi + hi@lo + lo@hi). Phase 1: A planes (global, dbuf in LDS)
// x W1 frags (global, L2-hot) -> H in LDS as hi/lo bf16 planes, pad 136
// (16B-aligned b128 reads, 8 acc/bank = conflict-free). Phase 2: H x W2 ->
// fp32 out. LDS union(A-dbuf 16K ushorts, H 2x17408) = 68KB -> 2 blocks/CU.
// NO __launch_bounds__ min-occupancy arg: R3/R4's (256,2) capped VGPR at 128
// vs ~170 live -> scratch spills in the K-loop (time invariant to structure).
#define HP 136
template <bool RELU_OUT>
__global__ __launch_bounds__(256) void mlp_kernel(
    const ushort* __restrict__ Ahi, const ushort* __restrict__ Alo,
    const ushort* __restrict__ W1hi, const ushort* __restrict__ W1lo,
    const ushort* __restrict__ W2hi, const ushort* __restrict__ W2lo,
    const float* __restrict__ b1, const float* __restrict__ gm,
    const float* __restrict__ bt, const float* __restrict__ rm,
    const float* __restrict__ rv, const float* __restrict__ b2,
    float* __restrict__ C, int M) {
    __shared__ __align__(16) ushort smem[2 * 128 * HP];   // 69632 B
    // A-dbuf view: AS(buf, plane, off), off in [0,4096)
#define AS(b_, p_, o_) smem[(((b_) * 2 + (p_)) << 12) + (o_)]
    // H view: HS(plane, off), off = row*HP + col
#define HS(p_, o_) smem[(p_)*128 * HP + (o_)]
    const int t = threadIdx.x;
    const int lane = t & 63;
    const int wv = t >> 6;
    const int wr = wv >> 1, wc = wv & 1;
    const int row0 = blockIdx.x * 128;
    const int g = lane >> 4, c = lane & 15;

    // staging map: 512 16B-segs per plane per kb; thread owns segs t, t+256.
    // LDS byte offset of seg s is exactly 16*s (lane-contiguous).
    const int m0 = t >> 2,  k80 = (t & 3) * 8;
    const int m1 = m0 + 64;
    int r0 = row0 + m0; if (r0 >= M) r0 = M - 1;
    int r1 = row0 + m1; if (r1 >= M) r1 = M - 1;
    const size_t ga0 = (size_t)r0 * 128 + k80;
    const size_t ga1 = (size_t)r1 * 128 + k80;
    const int la0 = m0 * 32 + k80, la1 = m1 * 32 + k80;

    f32x4 acc[4][4];
#pragma unroll
    for (int i = 0; i < 4; i++)
#pragma unroll
        for (int j = 0; j < 4; j++) acc[i][j] = (f32x4){0.f, 0.f, 0.f, 0.f};

    uint4 ph0 = *(const uint4*)(Ahi + ga0);
    uint4 ph1 = *(const uint4*)(Ahi + ga1);
    uint4 pl0 = *(const uint4*)(Alo + ga0);
    uint4 pl1 = *(const uint4*)(Alo + ga1);
    *(uint4*)&AS(0, 0, la0) = ph0;
    *(uint4*)&AS(0, 0, la1) = ph1;
    *(uint4*)&AS(0, 1, la0) = pl0;
    *(uint4*)&AS(0, 1, la1) = pl1;
    __syncthreads();

    // ---------------- phase 1: A @ W1
    int cur = 0;
    for (int kb = 0; kb < 4; kb++) {
        bf16x8 bh[4], bl[4];
#pragma unroll
        for (int ct = 0; ct < 4; ct++) {
            const size_t wo = (size_t)(wc * 64 + ct * 16 + c) * 128 + kb * 32 + g * 8;
            bh[ct] = *(const bf16x8*)(W1hi + wo);
            bl[ct] = *(const bf16x8*)(W1lo + wo);
        }
        if (kb < 3) {
            const size_t o = (size_t)(kb + 1) * 32;
            ph0 = *(const uint4*)(Ahi + ga0 + o);
            ph1 = *(const uint4*)(Ahi + ga1 + o);
            pl0 = *(const uint4*)(Alo + ga0 + o);
            pl1 = *(const uint4*)(Alo + ga1 + o);
        }
        bf16x8 ah[4], al[4];
#pragma unroll
        for (int rt = 0; rt < 4; rt++) {
            int off = (wr * 64 + rt * 16 + c) * 32 + g * 8;
            ah[rt] = *(bf16x8*)&AS(cur, 0, off);
            al[rt] = *(bf16x8*)&AS(cur, 1, off);
        }
#pragma unroll
        for (int rt = 0; rt < 4; rt++)
#pragma unroll
            for (int ct = 0; ct < 4; ct++) {
                acc[rt][ct] = __builtin_amdgcn_mfma_f32_16x16x32_bf16(ah[rt], bh[ct], acc[rt][ct], 0, 0, 0);
                acc[rt][ct] = __builtin_amdgcn_mfma_f32_16x16x32_bf16(ah[rt], bl[ct], acc[rt][ct], 0, 0, 0);
                acc[rt][ct] = __builtin_amdgcn_mfma_f32_16x16x32_bf16(al[rt], bh[ct], acc[rt][ct], 0, 0, 0);
            }
        if (kb < 3) {
            *(uint4*)&AS(cur ^ 1, 0, la0) = ph0;
            *(uint4*)&AS(cur ^ 1, 0, la1) = ph1;
            *(uint4*)&AS(cur ^ 1, 1, la0) = pl0;
            *(uint4*)&AS(cur ^ 1, 1, la1) = pl1;
        }
        __syncthreads();   // final iter: all As reads done -> H may alias
        cur ^= 1;
    }

    // ---------------- BN + ReLU -> H (hi/lo bf16) in LDS
    {
        float cs[4], ca[4];
#pragma unroll
        for (int ct = 0; ct < 4; ct++) {
            int n = wc * 64 + ct * 16 + c;
            float s = gm[n] * rsqrtf(rv[n] + BN_EPS);
            cs[ct] = s;
            ca[ct] = (b1[n] - rm[n]) * s + bt[n];
        }
#pragma unroll
        for (int rt = 0; rt < 4; rt++)
#pragma unroll
            for (int r = 0; r < 4; r++) {
                int row = wr * 64 + rt * 16 + g * 4 + r;
#pragma unroll
                for (int ct = 0; ct < 4; ct++) {
                    int col = wc * 64 + ct * 16 + c;
                    float v = fmaxf(acc[rt][ct][r] * cs[ct] + ca[ct], 0.f);
                    ushort hh, ll;
                    bf_split(v, hh, ll);
                    HS(0, row * HP + col) = hh;
                    HS(1, row * HP + col) = ll;
                }
            }
    }
    __syncthreads();

    // ---------------- phase 2: H @ W2
#pragma unroll
    for (int i = 0; i < 4; i++)
#pragma unroll
        for (int j = 0; j < 4; j++) acc[i][j] = (f32x4){0.f, 0.f, 0.f, 0.f};

    for (int kb = 0; kb < 4; kb++) {
        bf16x8 bh[4], bl[4];
#pragma unroll
        for (int ct = 0; ct < 4; ct++) {
            const size_t wo = (size_t)(wc * 64 + ct * 16 + c) * 128 + kb * 32 + g * 8;
            bh[ct] = *(const bf16x8*)(W2hi + wo);
            bl[ct] = *(const bf16x8*)(W2lo + wo);
        }
        bf16x8 ah[4], al[4];
#pragma unroll
        for (int rt = 0; rt < 4; rt++) {
            int off = (wr * 64 + rt * 16 + c) * HP + kb * 32 + g * 8;
            ah[rt] = *(bf16x8*)&HS(0, off);
            al[rt] = *(bf16x8*)&HS(1, off);
        }
#pragma unroll
        for (int rt = 0; rt < 4; rt++)
#pragma unroll
            for (int ct = 0; ct < 4; ct++) {
                acc[rt][ct] = __builtin_amdgcn_mfma_f32_16x16x32_bf16(ah[rt], bh[ct], acc[rt][ct], 0, 0, 0);
                acc[rt][ct] = __builtin_amdgcn_mfma_f32_16x16x32_bf16(ah[rt], bl[ct], acc[rt][ct], 0, 0, 0);
                acc[rt][ct] = __builtin_amdgcn_mfma_f32_16x16x32_bf16(al[rt], bh[ct], acc[rt][ct], 0, 0, 0);
            }
    }

    // ---------------- epilogue: +b2 (, ReLU) -> fp32
    float ca2[4];
#pragma unroll
    for (int ct = 0; ct < 4; ct++) ca2[ct] = b2[wc * 64 + ct * 16 + c];
#pragma unroll
    for (int rt = 0; rt < 4; rt++)
#pragma unroll
        for (int r = 0; r < 4; r++) {
            int row = row0 + wr * 64 + rt * 16 + g * 4 + r;
            if (row < M) {
#pragma unroll
                for (int ct = 0; ct < 4; ct++) {
                    int col = wc * 64 + ct * 16 + c;
                    float v = acc[rt][ct][r] + ca2[ct];
                    if (RELU_OUT) v = fmaxf(v, 0.f);
                    C[(size_t)row * 128 + col] = v;
                }
            }
        }
#undef AS
#undef HS
}

// ----------------------------------------------------------------- pooling
__global__ __launch_bounds__(384) void pool_kernel(const float* __restrict__ x1,
                                                   const float* __restrict__ x2,
                                                   const float* __restrict__ x3,
                                                   const int* __restrict__ batch,
                                                   float* __restrict__ pooled, int n) {
    __shared__ int bs[128];
    int b0 = blockIdx.x * 128;
    int t = threadIdx.x;
    int rows = n - b0; if (rows > 128) rows = 128;
    for (int i = t; i < rows; i += 384) bs[i] = batch[b0 + i];
    __syncthreads();
    const float* src = (t < 128) ? x1 : ((t < 256) ? x2 : x3);
    int ch = t & 127;
    int gcur = bs[0];
    float acc = 0.f;
#pragma unroll 8
    for (int r = 0; r < rows; r++) {
        int gg = bs[r];
        if (gg != gcur) {                       // block-uniform branch
            atomicAdd(&pooled[gcur * 384 + t], acc);
            acc = 0.f;
            gcur = gg;
        }
        acc += src[(size_t)(b0 + r) * 128 + ch];
    }
    atomicAdd(&pooled[gcur * 384 + t], acc);
}

__global__ __launch_bounds__(128) void final_kernel(const float* __restrict__ pooled,
                                                    const int* __restrict__ batch,
                                                    const float* __restrict__ W,
                                                    const float* __restrict__ b,
                                                    float* __restrict__ out, int n) {
    __shared__ float ps[384];
    int gph = blockIdx.x, t = threadIdx.x;
    int lo1 = 0, hi1 = n;
    while (lo1 < hi1) { int mid = (lo1 + hi1) >> 1; if (batch[mid] < gph) lo1 = mid + 1; else hi1 = mid; }
    int start = lo1;
    int lo2 = start, hi2 = n;
    while (lo2 < hi2) { int mid = (lo2 + hi2) >> 1; if (batch[mid] < gph + 1) lo2 = mid + 1; else hi2 = mid; }
    int cnt = lo2 - start;
    float inv = 1.f / (float)(cnt > 0 ? cnt : 1);
    for (int i = t; i < 384; i += 128) ps[i] = pooled[gph * 384 + i] * inv;
    __syncthreads();
    float acc = b[t];
#pragma unroll 8
    for (int k = 0; k < 384; k++) acc += ps[k] * W[k * 128 + t];
    out[gph * 128 + t] = acc;
}

// ------------------------------------------------------------------ launch
extern "C" void kernel_launch(void* const* d_in, const int* in_sizes, int n_in,
                              void* d_out, int out_size, void* d_ws, size_t ws_size,
                              hipStream_t stream) {
    const float* x     = (const float*)d_in[0];
    const int*   edge  = (const int*)d_in[1];
    const int*   batch = (const int*)d_in[2];
    const float* p[32];
    for (int i = 0; i < n_in && i < 32; i++) p[i] = (const float*)d_in[i];
    const float* lin_W = p[27];
    const float* lin_b = p[28];

    char* w = (char*)d_ws;
    auto alloc = [&](size_t bytes) { void* r = (void*)w; w += (bytes + 255) & ~(size_t)255; return r; };
    const size_t PL = (size_t)NNODES * 128;          // plane elements
    ushort* thi = (ushort*)alloc(PL * 2);
    ushort* tlo = (ushort*)alloc(PL * 2);
    float* x1     = (float*)alloc(PL * 4);
    float* x2b    = (float*)alloc(PL * 4);
    float* x3b    = (float*)alloc(PL * 4);
    float* pooled = (float*)alloc((size_t)NGRAPHS * 384 * 4);
    int* counts   = (int*)alloc((size_t)NNODES * 4);
    int* cursor   = (int*)alloc((size_t)NNODES * 4);
    int* row_ptr  = (int*)alloc((size_t)(NNODES + 1) * 4);
    int* esrc     = (int*)alloc((size_t)NEDGES * 4);
    int* partials = (int*)alloc(256 * 4);
    ushort* wt_hi = (ushort*)alloc((size_t)6 * 16384 * 2);
    ushort* wt_lo = (ushort*)alloc((size_t)6 * 16384 * 2);

    const int* src = edge;
    const int* dst = edge + NEDGES;

    // --- weight split/transpose (6 matrices)
    wsplit_kernel<<<dim3(16, 6), 256, 0, stream>>>(p[3], p[9], p[11], p[17], p[19], p[25],
                                                   wt_hi, wt_lo);

    // --- CSR build (reused by all 3 layers)
    hipMemsetAsync(counts, 0, (size_t)NNODES * 4, stream);
    hipMemsetAsync(pooled, 0, (size_t)NGRAPHS * 384 * 4, stream);
    hist_kernel<<<(NEDGES + 255) / 256, 256, 0, stream>>>(dst, counts, NEDGES);
    int nb = (NNODES + 255) / 256;  // 196
    scan1_kernel<<<nb, 256, 0, stream>>>(counts, partials, NNODES);
    scan2_kernel<<<1, 256, 0, stream>>>(partials, nb, row_ptr, NEDGES);
    scan3_kernel<<<nb, 256, 0, stream>>>(counts, partials, row_ptr, cursor, NNODES);
    scatter_kernel<<<(NEDGES + 255) / 256, 256, 0, stream>>>(src, dst, cursor, esrc, NEDGES);

    // --- 3 GIN layers (agg -> fused MLP)
    int gemm_grid = (NNODES + 127) / 128;               // 391
    int agg_grid = (NNODES / 2 * 64 + 255) / 256;       // 2 nodes/wave
    const float* xin = x;
    float* fouts[3] = {x1, x2b, x3b};
    for (int li = 0; li < 3; li++) {
        const float* b1 = p[4 + 8 * li];
        const float* gm = p[5 + 8 * li];
        const float* bt = p[6 + 8 * li];
        const float* rm = p[7 + 8 * li];
        const float* rv = p[8 + 8 * li];
        const float* b2 = p[10 + 8 * li];
        const ushort* w1h = wt_hi + (size_t)(2 * li) * 16384;
        const ushort* w1l = wt_lo + (size_t)(2 * li) * 16384;
        const ushort* w2h = wt_hi + (size_t)(2 * li + 1) * 16384;
        const ushort* w2l = wt_lo + (size_t)(2 * li + 1) * 16384;

        agg_kernel<<<agg_grid, 256, 0, stream>>>(xin, row_ptr, esrc, thi, tlo, NNODES);
        if (li < 2)
            mlp_kernel<true><<<gemm_grid, 256, 0, stream>>>(thi, tlo, w1h, w1l, w2h, w2l,
                                                            b1, gm, bt, rm, rv, b2,
                                                            fouts[li], NNODES);
        else
            mlp_kernel<false><<<gemm_grid, 256, 0, stream>>>(thi, tlo, w1h, w1l, w2h, w2l,
                                                             b1, gm, bt, rm, rv, b2,
                                                             fouts[li], NNODES);
        xin = fouts[li];
    }

    // --- JK-concat mean pool + final linear
    pool_kernel<<<(NNODES + 127) / 128, 384, 0, stream>>>(x1, x2b, x3b, batch, pooled, NNODES);
    final_kernel<<<NGRAPHS, 128, 0, stream>>>(pooled, batch, lin_W, lin_b, (float*)d_out, NNODES);
}